// Round 4
// baseline (334.099 us; speedup 1.0000x reference)
//
#include <hip/hip_runtime.h>
#include <math.h>

#define H 96
#define W 96
#define HW 9216
#define B 8
#define CIN 256
#define CM 64
#define NPOS (B*HW)    /* 73728 */
#define NBLK (NPOS/64) /* 1152 = 8 XCDs x 144 */

/* XCD swizzle: round-robin dispatch -> XCD g owns one batch image (2.25MB, fits 4MB L2).
   Applied to ALL per-position kernels so producer and consumer L2 match. */
__device__ __forceinline__ int xswiz(int n) { return (n & 7) * 144 + (n >> 3); }

typedef float  f32x4  __attribute__((ext_vector_type(4)));
typedef short  bf16x8 __attribute__((ext_vector_type(8)));

/* workspace layout (float offsets) */
#define OFF_WDBO  0         /* 9216 f = 18432 bf16: woff B-frags [kc18][nt2][lane][8] */
#define OFF_BNS   9216      /* 64 */
#define OFF_BNB   9280      /* 64 */
#define OFF_WDB1  9344      /* 8192 f = 16384 bf16: w1 B-frags [kc8][nt4][lane][8] */
#define OFF_WDB3  17536     /* 18432 f = 36864 bf16: wd B-frags [kc18][nt4][lane][8] */
#define OFF_WDB2  35968     /* 8192 f = 16384 bf16: w2 B-frags [kc2][nt16][lane][8] */
#define OFF_FCL   44160     /* 4718592: fcl[b][hw][64] channels-last fp32 */

/* round-to-nearest-even fp32 -> bf16 (bit pattern in low 16) */
__device__ __forceinline__ unsigned bfbits(float f) {
  union { float f; unsigned u; } c;
  c.f = f;
  return (c.u + 0x7FFFu + ((c.u >> 16) & 1u)) >> 16;
}
__device__ __forceinline__ short f2bf(float f) { return (short)bfbits(f); }
__device__ __forceinline__ unsigned pack2(float lo, float hi) {
  return bfbits(lo) | (bfbits(hi) << 16);
}

/* k0: weight reformat. B-frag layout for mfma_f32_16x16x32_bf16:
   B[k][n], n = nt*16 + (lane&15), k = kc*32 + (lane>>4)*8 + j  (j=0..7 contiguous) */
__global__ __launch_bounds__(256) void k0_prep(
    const float* __restrict__ w1, const float* __restrict__ woff,
    const float* __restrict__ wd, const float* __restrict__ w2,
    const float* __restrict__ gamma, const float* __restrict__ beta,
    const float* __restrict__ rmean, const float* __restrict__ rvar,
    float* __restrict__ ws) {
  int i = blockIdx.x * 256 + threadIdx.x;
  if (i < 18432) {                      /* wdbo: K=(ks*64+c)(576), N=o(18,pad32) */
    int j = i;
    int j8 = j & 7, lane = (j >> 3) & 63, nt = (j >> 9) & 1, kc = j >> 10;
    int n = nt * 16 + (lane & 15);
    int c = (kc & 1) * 32 + ((lane >> 4) & 3) * 8 + j8;
    int ks = kc >> 1;
    ((short*)(ws + OFF_WDBO))[j] = (n < 18) ? f2bf(woff[(n * 64 + c) * 9 + ks]) : (short)0;
  } else if (i < 18496) {               /* BN folding */
    int o = i - 18432;
    float inv = gamma[o] / sqrtf(rvar[o] + 1e-5f);
    ws[OFF_BNS + o] = inv;
    ws[OFF_BNB + o] = beta[o] - rmean[o] * inv;
  } else if (i < 34880) {               /* wdb1: K=c(256), N=o(64) from w1[o][c] */
    int j = i - 18496;
    int j8 = j & 7, lane = (j >> 3) & 63, nt = (j >> 9) & 3, kc = j >> 11;
    int n = nt * 16 + (lane & 15);
    int c = kc * 32 + ((lane >> 4) & 3) * 8 + j8;
    ((short*)(ws + OFF_WDB1))[j] = f2bf(w1[n * 256 + c]);
  } else if (i < 71744) {               /* wdb3: K=(kstep*64+c)(576), N=o from wd[o][c][kstep] */
    int j = i - 34880;
    int j8 = j & 7, lane = (j >> 3) & 63, nt = (j >> 9) & 3, kc = j >> 11;
    int n = nt * 16 + (lane & 15);
    int c = (kc & 1) * 32 + ((lane >> 4) & 3) * 8 + j8;
    int ks = kc >> 1;
    ((short*)(ws + OFF_WDB3))[j] = f2bf(wd[(n * 64 + c) * 9 + ks]);
  } else if (i < 88128) {               /* wdb2: K=c(64), N=o(256) from w2[o][c] */
    int j = i - 71744;
    int j8 = j & 7, lane = (j >> 3) & 63, nt = (j >> 9) & 15, kc = j >> 13;
    int n = nt * 16 + (lane & 15);
    int c = kc * 32 + ((lane >> 4) & 3) * 8 + j8;
    ((short*)(ws + OFF_WDB2))[j] = f2bf(w2[n * 64 + c]);
  }
}

/* k1: pwconv1 via MFMA. M=64 pos, N=64 o, K=256. ALL 64 x-loads issued up-front
   (max MLP against ~900cy HBM latency), consumed kc-by-kc. */
__global__ __launch_bounds__(256) void k1_pw1(
    const float* __restrict__ x, const short* __restrict__ wdb1,
    const float* __restrict__ b1, float* __restrict__ fcl) {
  __shared__ float sA[64 * 66];  /* epilogue transpose only */
  int t = threadIdx.x;
  int lane = t & 63;
  int qq = __builtin_amdgcn_readfirstlane(t >> 6);
  int quad = lane >> 4, l15 = lane & 15;
  int gpos0 = xswiz(blockIdx.x) * 64;
  int b = gpos0 / HW, hw0 = gpos0 - b * HW;
  const float* xp = x + (size_t)b * CIN * HW + (size_t)(quad * 8) * HW + hw0 + qq * 16 + l15;

  float v[8][8];
#pragma unroll
  for (int kc = 0; kc < 8; kc++)
#pragma unroll
    for (int jj = 0; jj < 8; jj++)
      v[kc][jj] = xp[(size_t)(kc * 32 + jj) * HW];

  f32x4 acc[4];
#pragma unroll
  for (int nt = 0; nt < 4; nt++) acc[nt] = (f32x4){0.f, 0.f, 0.f, 0.f};
#pragma unroll
  for (int kc = 0; kc < 8; kc++) {
    union { unsigned u[4]; bf16x8 f; } af;
    af.u[0] = pack2(v[kc][0], v[kc][1]); af.u[1] = pack2(v[kc][2], v[kc][3]);
    af.u[2] = pack2(v[kc][4], v[kc][5]); af.u[3] = pack2(v[kc][6], v[kc][7]);
#pragma unroll
    for (int nt = 0; nt < 4; nt++) {
      bf16x8 bf = ((const bf16x8*)wdb1)[(kc * 4 + nt) * 64 + lane];
      acc[nt] = __builtin_amdgcn_mfma_f32_16x16x32_bf16(af.f, bf, acc[nt], 0, 0, 0);
    }
  }
  /* epilogue: D[m=qq*16+quad*4+reg][o=nt*16+l15] + bias -> LDS -> fcl rows */
#pragma unroll
  for (int nt = 0; nt < 4; nt++) {
    int o = nt * 16 + l15;
#pragma unroll
    for (int reg = 0; reg < 4; reg++) {
      int m = qq * 16 + quad * 4 + reg;
      sA[m * 66 + o] = acc[nt][reg] + b1[o];
    }
  }
  __syncthreads();
  for (int rr = t; rr < 4096; rr += 256) {
    int p2 = rr >> 6, o2 = rr & 63;
    fcl[(size_t)(gpos0 + p2) * 64 + o2] = sA[p2 * 66 + o2];
  }
}

/* k234: FUSED offset-conv + deformable-conv+BN + pwconv2+gate.
   All three phases share the same 64-position block; glue tensors (offs 4.6KB,
   vcl 8KB bf16) live in LDS instead of round-tripping through global.
   LDS phase-aliasing:
     R1 (18432B): tiw[576][4] (tap table)      -> k4-epilogue sA[64*66] f32
     R2 (18432B): sP[64*34] f32 (offs)         -> sAb[2][64*72] bf16 A-tiles
   Phase access patterns are verbatim from the round-3 standalone kernels. */
__global__ __launch_bounds__(256, 3) void k234(
    const float* __restrict__ fcl, const short* __restrict__ wdbo,
    const float* __restrict__ boff, const short* __restrict__ wdb3,
    const float* __restrict__ bd, const float* __restrict__ bns,
    const float* __restrict__ bnb, const short* __restrict__ wdb2,
    const float* __restrict__ b2, const float* __restrict__ x,
    float* __restrict__ out) {
  __shared__ __align__(16) char R1[18432];
  __shared__ __align__(16) char R2[18432];
  int t = threadIdx.x;
  int lane = t & 63;
  int qq = __builtin_amdgcn_readfirstlane(t >> 6);
  int quad = lane >> 4, l15 = lane & 15;
  int mrow = qq * 16 + l15;
  int gpos0 = xswiz(blockIdx.x) * 64;
  int b = gpos0 / HW, hw0 = gpos0 - b * HW;

  /* ===== phase A: offset conv (MFMA im2col, depth-1 prefetch) ===== */
  {
    int m = mrow;
    int hw = hw0 + m, i = hw / W, j = hw - i * W;
    const float* base = fcl + (size_t)(gpos0 + m) * 64 + quad * 8;
    f32x4 acc2[2];
    acc2[0] = (f32x4){0.f, 0.f, 0.f, 0.f};
    acc2[1] = (f32x4){0.f, 0.f, 0.f, 0.f};

    f32x4 va0, vb0, va1, vb1;
    bool okc;
    { /* tap 0: dy=-1,dx=-1 */
      okc = (i >= 1) && (j >= 1);
      const float* s = base + (okc ? (-W - 1) * 64 : 0);
      va0 = *(const f32x4*)(s);      vb0 = *(const f32x4*)(s + 4);
      va1 = *(const f32x4*)(s + 32); vb1 = *(const f32x4*)(s + 36);
    }
#pragma unroll
    for (int ks = 0; ks < 9; ks++) {
      f32x4 z = (f32x4){0.f, 0.f, 0.f, 0.f};
      f32x4 a0 = okc ? va0 : z, c0 = okc ? vb0 : z;
      f32x4 a1 = okc ? va1 : z, c1 = okc ? vb1 : z;
      union { unsigned u[4]; bf16x8 f; } f0, f1;
      f0.u[0] = pack2(a0[0], a0[1]); f0.u[1] = pack2(a0[2], a0[3]);
      f0.u[2] = pack2(c0[0], c0[1]); f0.u[3] = pack2(c0[2], c0[3]);
      f1.u[0] = pack2(a1[0], a1[1]); f1.u[1] = pack2(a1[2], a1[3]);
      f1.u[2] = pack2(c1[0], c1[1]); f1.u[3] = pack2(c1[2], c1[3]);
      if (ks < 8) { /* prefetch next tap */
        int kn = ks + 1, dy = kn / 3 - 1, dx = kn % 3 - 1;
        okc = ((unsigned)(i + dy) < (unsigned)H) && ((unsigned)(j + dx) < (unsigned)W);
        const float* s = base + (okc ? (dy * W + dx) * 64 : 0);
        va0 = *(const f32x4*)(s);      vb0 = *(const f32x4*)(s + 4);
        va1 = *(const f32x4*)(s + 32); vb1 = *(const f32x4*)(s + 36);
      }
      bf16x8 bf00 = ((const bf16x8*)wdbo)[((ks * 2 + 0) * 2 + 0) * 64 + lane];
      bf16x8 bf01 = ((const bf16x8*)wdbo)[((ks * 2 + 0) * 2 + 1) * 64 + lane];
      bf16x8 bf10 = ((const bf16x8*)wdbo)[((ks * 2 + 1) * 2 + 0) * 64 + lane];
      bf16x8 bf11 = ((const bf16x8*)wdbo)[((ks * 2 + 1) * 2 + 1) * 64 + lane];
      acc2[0] = __builtin_amdgcn_mfma_f32_16x16x32_bf16(f0.f, bf00, acc2[0], 0, 0, 0);
      acc2[1] = __builtin_amdgcn_mfma_f32_16x16x32_bf16(f0.f, bf01, acc2[1], 0, 0, 0);
      acc2[0] = __builtin_amdgcn_mfma_f32_16x16x32_bf16(f1.f, bf10, acc2[0], 0, 0, 0);
      acc2[1] = __builtin_amdgcn_mfma_f32_16x16x32_bf16(f1.f, bf11, acc2[1], 0, 0, 0);
    }
    /* D[m][o] + boff -> sP (offs for this block's 64 positions, channels 0..31) */
    float* sP = (float*)R2;
    float bo0 = boff[l15];                            /* o = l15 < 16 */
    float bo1 = (16 + l15 < 18) ? boff[16 + l15] : 0.f;
#pragma unroll
    for (int reg = 0; reg < 4; reg++) {
      int mm = qq * 16 + quad * 4 + reg;
      sP[mm * 34 + l15]      = acc2[0][reg] + bo0;
      sP[mm * 34 + 16 + l15] = acc2[1][reg] + bo1;
    }
  }
  __syncthreads();

  /* ===== phase B: tap precompute (wave qq handles k = qq, qq+4, ...) ===== */
  {
    const float* sP = (const float*)R2;
    int2 (*tiw)[4] = (int2(*)[4])R1;
    int hw = hw0 + lane;
    int i = hw / W, j = hw - i * W;
    for (int k = qq; k < 9; k += 4) {
      float dy = sP[lane * 34 + 2 * k + 0];
      float dx = sP[lane * 34 + 2 * k + 1];
      float py = (float)(i + k / 3 - 1) + dy;
      float px = (float)(j + k % 3 - 1) + dx;
      float y0f = floorf(py), x0f = floorf(px);
      int y0 = (int)y0f, x0 = (int)x0f;
      float fy = py - y0f, fx = px - x0f;
      float w00 = (1.f - fy) * (1.f - fx), w01 = (1.f - fy) * fx;
      float w10 = fy * (1.f - fx), w11 = fy * fx;
      bool vy0 = (y0 >= 0) && (y0 < H), vy1 = (y0 + 1 >= 0) && (y0 + 1 < H);
      bool vx0 = (x0 >= 0) && (x0 < W), vx1 = (x0 + 1 >= 0) && (x0 + 1 < W);
      if (!(vy0 && vx0)) w00 = 0.f;
      if (!(vy0 && vx1)) w01 = 0.f;
      if (!(vy1 && vx0)) w10 = 0.f;
      if (!(vy1 && vx1)) w11 = 0.f;
      int yi0 = min(max(y0, 0), H - 1), yi1 = min(max(y0 + 1, 0), H - 1);
      int xi0 = min(max(x0, 0), W - 1), xi1 = min(max(x0 + 1, 0), W - 1);
      int e = k * 64 + lane;
      tiw[e][0] = make_int2((yi0 * W + xi0) * 256, __float_as_int(w00));
      tiw[e][1] = make_int2((yi0 * W + xi1) * 256, __float_as_int(w01));
      tiw[e][2] = make_int2((yi1 * W + xi0) * 256, __float_as_int(w10));
      tiw[e][3] = make_int2((yi1 * W + xi1) * 256, __float_as_int(w11));
    }
  }
  __syncthreads();

  /* ===== phase C: deformable conv main loop (ring-pipelined gathers) ===== */
  short* sAb = (short*)R2;                 /* [2][64*72] ping-pong bf16 A-tiles */
  const int2 (*tiw)[4] = (const int2(*)[4])R1;
  const char* fb = (const char*)fcl + (size_t)b * HW * 256;
  int c2 = lane & 31;          /* channel pair: channels 2c2, 2c2+1 */
  int c28 = c2 * 8;
  int half = lane >> 5;        /* which of the 2 positions this lane samples */
  int parow = qq * 16 + half;  /* pa = parow + pp*2 */

  float2 sv[8][4];             /* sampled values ring (in flight) */
  float  sw[8][4];             /* their bilinear weights */
  f32x4 acc3[4];
#pragma unroll
  for (int nt = 0; nt < 4; nt++) acc3[nt] = (f32x4){0.f, 0.f, 0.f, 0.f};

  auto issue = [&](int ks, int pp) {
    int e = ks * 64 + parow + pp * 2;
    int4 q0 = *(const int4*)&tiw[e][0];
    int4 q1 = *(const int4*)&tiw[e][2];
    sv[pp][0] = *(const float2*)(fb + (q0.x + c28)); sw[pp][0] = __int_as_float(q0.y);
    sv[pp][1] = *(const float2*)(fb + (q0.z + c28)); sw[pp][1] = __int_as_float(q0.w);
    sv[pp][2] = *(const float2*)(fb + (q1.x + c28)); sw[pp][2] = __int_as_float(q1.y);
    sv[pp][3] = *(const float2*)(fb + (q1.z + c28)); sw[pp][3] = __int_as_float(q1.w);
  };
  auto consume = [&](int pp, int bi) {
    int pa = parow + pp * 2;
    float slo = sw[pp][0] * sv[pp][0].x + sw[pp][1] * sv[pp][1].x +
                sw[pp][2] * sv[pp][2].x + sw[pp][3] * sv[pp][3].x;
    float shi = sw[pp][0] * sv[pp][0].y + sw[pp][1] * sv[pp][1].y +
                sw[pp][2] * sv[pp][2].y + sw[pp][3] * sv[pp][3].y;
    ((unsigned*)(sAb + bi * 64 * 72))[pa * 36 + c2] = pack2(slo, shi);
  };
  auto mfmastep = [&](int ks, int bi) {
#pragma unroll
    for (int ch = 0; ch < 2; ch++) {
      bf16x8 af = *(const bf16x8*)&sAb[bi * 64 * 72 + mrow * 72 + ch * 32 + quad * 8];
      int kc = ks * 2 + ch;
#pragma unroll
      for (int nt = 0; nt < 4; nt++) {
        bf16x8 bf = ((const bf16x8*)wdb3)[(kc * 4 + nt) * 64 + lane];
        acc3[nt] = __builtin_amdgcn_mfma_f32_16x16x32_bf16(af, bf, acc3[nt], 0, 0, 0);
      }
    }
  };

#pragma unroll
  for (int pp = 0; pp < 8; pp++) issue(0, pp);
  for (int ks = 0; ks < 8; ks++) {
    int bi = ks & 1;
#pragma unroll
    for (int pp = 0; pp < 8; pp++) {
      consume(pp, bi);
      issue(ks + 1, pp);
    }
    mfmastep(ks, bi);
  }
#pragma unroll
  for (int pp = 0; pp < 8; pp++) consume(pp, 0);
  mfmastep(8, 0);

  /* ===== phase D: BN + bf16, wave-private rows of sAb[0] (= vcl tile) ===== */
#pragma unroll
  for (int nt = 0; nt < 4; nt++) {
    int o = nt * 16 + l15;
    float sc = bns[o], sb = bnb[o], bb = bd[o];
#pragma unroll
    for (int reg = 0; reg < 4; reg++) {
      int m = qq * 16 + quad * 4 + reg;
      sAb[m * 72 + o] = f2bf((acc3[nt][reg] + bb) * sc + sb);
    }
  }
  /* no barrier: phase-E A-frag reads are wave-private rows */

  /* ===== phase E: pwconv2 MFMA (M=64, N=256, K=64) ===== */
  bf16x8 af0 = *(const bf16x8*)&sAb[mrow * 72 + quad * 8];
  bf16x8 af1 = *(const bf16x8*)&sAb[mrow * 72 + 32 + quad * 8];
  f32x4 acc4[16];
#pragma unroll
  for (int nt = 0; nt < 16; nt++) acc4[nt] = (f32x4){0.f, 0.f, 0.f, 0.f};
#pragma unroll
  for (int nt = 0; nt < 16; nt++) {
    bf16x8 bf0 = ((const bf16x8*)wdb2)[(0 * 16 + nt) * 64 + lane];
    bf16x8 bf1 = ((const bf16x8*)wdb2)[(1 * 16 + nt) * 64 + lane];
    acc4[nt] = __builtin_amdgcn_mfma_f32_16x16x32_bf16(af0, bf0, acc4[nt], 0, 0, 0);
    acc4[nt] = __builtin_amdgcn_mfma_f32_16x16x32_bf16(af1, bf1, acc4[nt], 0, 0, 0);
  }

  /* ===== phase F: gate epilogue, 4 chunks of 64 out-channels via R1 ===== */
  float* sA = (float*)R1;   /* tiw dead after phase C; barrier below protects */
  for (int nc = 0; nc < 4; nc++) {
    __syncthreads();
#pragma unroll
    for (int nt2 = 0; nt2 < 4; nt2++) {
      int nt = nc * 4 + nt2;
      int o1 = nt2 * 16 + l15;
#pragma unroll
      for (int reg = 0; reg < 4; reg++) {
        int m = qq * 16 + quad * 4 + reg;
        sA[m * 66 + o1] = acc4[nt][reg] + b2[nc * 64 + nt2 * 16 + l15];
      }
    }
    __syncthreads();
    for (int rr = t; rr < 4096; rr += 256) {
      int o1 = rr >> 6, p = rr & 63;
      int o = nc * 64 + o1;
      float wv = sA[p * 66 + o1];
      float sg = 1.f / (1.f + __expf(-wv));
      size_t gi = ((size_t)b * CIN + o) * HW + hw0 + p;
      out[gi] = x[gi] * sg;
    }
  }
}

extern "C" void kernel_launch(void* const* d_in, const int* in_sizes, int n_in,
                              void* d_out, int out_size, void* d_ws, size_t ws_size,
                              hipStream_t stream) {
  const float* x     = (const float*)d_in[0];
  const float* w1    = (const float*)d_in[1];
  const float* b1    = (const float*)d_in[2];
  const float* woff  = (const float*)d_in[3];
  const float* boff  = (const float*)d_in[4];
  const float* wd    = (const float*)d_in[5];
  const float* bd    = (const float*)d_in[6];
  const float* gamma = (const float*)d_in[7];
  const float* beta  = (const float*)d_in[8];
  const float* rmean = (const float*)d_in[9];
  const float* rvar  = (const float*)d_in[10];
  const float* w2    = (const float*)d_in[11];
  const float* b2    = (const float*)d_in[12];
  float* out = (float*)d_out;
  float* ws  = (float*)d_ws;

  dim3 blk(256);
  k0_prep<<<dim3(345), blk, 0, stream>>>(w1, woff, wd, w2, gamma, beta, rmean, rvar, ws);
  k1_pw1<<<dim3(NBLK), blk, 0, stream>>>(x, (const short*)(ws + OFF_WDB1), b1, ws + OFF_FCL);
  k234<<<dim3(NBLK), blk, 0, stream>>>(ws + OFF_FCL, (const short*)(ws + OFF_WDBO), boff,
                                       (const short*)(ws + OFF_WDB3), bd,
                                       ws + OFF_BNS, ws + OFF_BNB,
                                       (const short*)(ws + OFF_WDB2), b2, x, out);
}

// Round 6
// 259.306 us; speedup vs baseline: 1.2884x; 1.2884x over previous
//
#include <hip/hip_runtime.h>
#include <math.h>

#define H 96
#define W 96
#define HW 9216
#define B 8
#define CIN 256
#define CM 64
#define NPOS (B*HW)    /* 73728 */
#define NBLK (NPOS/64) /* 1152 = 8 XCDs x 144 */

/* XCD swizzle: round-robin dispatch -> XCD g owns one batch image (2.25MB, fits 4MB L2). */
__device__ __forceinline__ int xswiz(int n) { return (n & 7) * 144 + (n >> 3); }

typedef float  f32x4  __attribute__((ext_vector_type(4)));
typedef short  bf16x8 __attribute__((ext_vector_type(8)));

/* workspace layout (float offsets) */
#define OFF_WDBO  0         /* 9216 f = 18432 bf16: woff B-frags [kc18][nt2][lane][8] */
#define OFF_BNS   9216      /* 64 */
#define OFF_BNB   9280      /* 64 */
#define OFF_WDB1  9344      /* 8192 f = 16384 bf16: w1 B-frags [kc8][nt4][lane][8] */
#define OFF_WDB3  17536     /* 18432 f = 36864 bf16: wd B-frags [kc18][nt4][lane][8] */
#define OFF_WDB2  35968     /* 8192 f = 16384 bf16: w2 B-frags [kc2][nt16][lane][8] */
#define OFF_FCL   44160     /* 4718592: fcl[b][hw][64] channels-last fp32 */

/* round-to-nearest-even fp32 -> bf16 (bit pattern in low 16) */
__device__ __forceinline__ unsigned bfbits(float f) {
  union { float f; unsigned u; } c;
  c.f = f;
  return (c.u + 0x7FFFu + ((c.u >> 16) & 1u)) >> 16;
}
__device__ __forceinline__ short f2bf(float f) { return (short)bfbits(f); }
__device__ __forceinline__ unsigned pack2(float lo, float hi) {
  return bfbits(lo) | (bfbits(hi) << 16);
}

/* k0: weight reformat. B-frag layout for mfma_f32_16x16x32_bf16:
   B[k][n], n = nt*16 + (lane&15), k = kc*32 + (lane>>4)*8 + j  (j=0..7 contiguous) */
__global__ __launch_bounds__(256) void k0_prep(
    const float* __restrict__ w1, const float* __restrict__ woff,
    const float* __restrict__ wd, const float* __restrict__ w2,
    const float* __restrict__ gamma, const float* __restrict__ beta,
    const float* __restrict__ rmean, const float* __restrict__ rvar,
    float* __restrict__ ws) {
  int i = blockIdx.x * 256 + threadIdx.x;
  if (i < 18432) {                      /* wdbo: K=(ks*64+c)(576), N=o(18,pad32) */
    int j = i;
    int j8 = j & 7, lane = (j >> 3) & 63, nt = (j >> 9) & 1, kc = j >> 10;
    int n = nt * 16 + (lane & 15);
    int c = (kc & 1) * 32 + ((lane >> 4) & 3) * 8 + j8;
    int ks = kc >> 1;
    ((short*)(ws + OFF_WDBO))[j] = (n < 18) ? f2bf(woff[(n * 64 + c) * 9 + ks]) : (short)0;
  } else if (i < 18496) {               /* BN folding */
    int o = i - 18432;
    float inv = gamma[o] / sqrtf(rvar[o] + 1e-5f);
    ws[OFF_BNS + o] = inv;
    ws[OFF_BNB + o] = beta[o] - rmean[o] * inv;
  } else if (i < 34880) {               /* wdb1: K=c(256), N=o(64) from w1[o][c] */
    int j = i - 18496;
    int j8 = j & 7, lane = (j >> 3) & 63, nt = (j >> 9) & 3, kc = j >> 11;
    int n = nt * 16 + (lane & 15);
    int c = kc * 32 + ((lane >> 4) & 3) * 8 + j8;
    ((short*)(ws + OFF_WDB1))[j] = f2bf(w1[n * 256 + c]);
  } else if (i < 71744) {               /* wdb3: K=(kstep*64+c)(576), N=o from wd[o][c][kstep] */
    int j = i - 34880;
    int j8 = j & 7, lane = (j >> 3) & 63, nt = (j >> 9) & 3, kc = j >> 11;
    int n = nt * 16 + (lane & 15);
    int c = (kc & 1) * 32 + ((lane >> 4) & 3) * 8 + j8;
    int ks = kc >> 1;
    ((short*)(ws + OFF_WDB3))[j] = f2bf(wd[(n * 64 + c) * 9 + ks]);
  } else if (i < 88128) {               /* wdb2: K=c(64), N=o(256) from w2[o][c] */
    int j = i - 71744;
    int j8 = j & 7, lane = (j >> 3) & 63, nt = (j >> 9) & 15, kc = j >> 13;
    int n = nt * 16 + (lane & 15);
    int c = kc * 32 + ((lane >> 4) & 3) * 8 + j8;
    ((short*)(ws + OFF_WDB2))[j] = f2bf(w2[n * 64 + c]);
  }
}

/* k1: pwconv1 via MFMA. M=64 pos, N=64 o, K=256. ALL 64 x-loads issued up-front. */
__global__ __launch_bounds__(256) void k1_pw1(
    const float* __restrict__ x, const short* __restrict__ wdb1,
    const float* __restrict__ b1, float* __restrict__ fcl) {
  __shared__ float sA[64 * 66];  /* epilogue transpose only */
  int t = threadIdx.x;
  int lane = t & 63;
  int qq = __builtin_amdgcn_readfirstlane(t >> 6);
  int quad = lane >> 4, l15 = lane & 15;
  int gpos0 = xswiz(blockIdx.x) * 64;
  int b = gpos0 / HW, hw0 = gpos0 - b * HW;
  const float* xp = x + (size_t)b * CIN * HW + (size_t)(quad * 8) * HW + hw0 + qq * 16 + l15;

  float v[8][8];
#pragma unroll
  for (int kc = 0; kc < 8; kc++)
#pragma unroll
    for (int jj = 0; jj < 8; jj++)
      v[kc][jj] = xp[(size_t)(kc * 32 + jj) * HW];

  f32x4 acc[4];
#pragma unroll
  for (int nt = 0; nt < 4; nt++) acc[nt] = (f32x4){0.f, 0.f, 0.f, 0.f};
#pragma unroll
  for (int kc = 0; kc < 8; kc++) {
    union { unsigned u[4]; bf16x8 f; } af;
    af.u[0] = pack2(v[kc][0], v[kc][1]); af.u[1] = pack2(v[kc][2], v[kc][3]);
    af.u[2] = pack2(v[kc][4], v[kc][5]); af.u[3] = pack2(v[kc][6], v[kc][7]);
#pragma unroll
    for (int nt = 0; nt < 4; nt++) {
      bf16x8 bf = ((const bf16x8*)wdb1)[(kc * 4 + nt) * 64 + lane];
      acc[nt] = __builtin_amdgcn_mfma_f32_16x16x32_bf16(af.f, bf, acc[nt], 0, 0, 0);
    }
  }
#pragma unroll
  for (int nt = 0; nt < 4; nt++) {
    int o = nt * 16 + l15;
#pragma unroll
    for (int reg = 0; reg < 4; reg++) {
      int m = qq * 16 + quad * 4 + reg;
      sA[m * 66 + o] = acc[nt][reg] + b1[o];
    }
  }
  __syncthreads();
  for (int rr = t; rr < 4096; rr += 256) {
    int p2 = rr >> 6, o2 = rr & 63;
    fcl[(size_t)(gpos0 + p2) * 64 + o2] = sA[p2 * 66 + o2];
  }
}

/* k234: FUSED offset-conv + deformable-conv+BN + pwconv2+gate.
   Ring of 4 NAMED Slot structs (statically-indexed members -> registers),
   single A-tile (no ping-pong), pwconv2 chunked to acc4[4].
   LDS: R1 18432B (tiw[576][4] -> sA[64][68] f32), R2 9216B (sP -> sAb). */
__global__ __launch_bounds__(256, 3) void k234(
    const float* __restrict__ fcl, const short* __restrict__ wdbo,
    const float* __restrict__ boff, const short* __restrict__ wdb3,
    const float* __restrict__ bd, const float* __restrict__ bns,
    const float* __restrict__ bnb, const short* __restrict__ wdb2,
    const float* __restrict__ b2, const float* __restrict__ x,
    float* __restrict__ out) {
  __shared__ __align__(16) char R1[18432];
  __shared__ __align__(16) char R2[9216];
  int t = threadIdx.x;
  int lane = t & 63;
  int qq = __builtin_amdgcn_readfirstlane(t >> 6);
  int quad = lane >> 4, l15 = lane & 15;
  int mrow = qq * 16 + l15;
  int gpos0 = xswiz(blockIdx.x) * 64;
  int b = gpos0 / HW, hw0 = gpos0 - b * HW;

  /* ===== phase A: offset conv (MFMA im2col, depth-1 prefetch) ===== */
  {
    int m = mrow;
    int hw = hw0 + m, i = hw / W, j = hw - i * W;
    const float* base = fcl + (size_t)(gpos0 + m) * 64 + quad * 8;
    f32x4 acc2[2];
    acc2[0] = (f32x4){0.f, 0.f, 0.f, 0.f};
    acc2[1] = (f32x4){0.f, 0.f, 0.f, 0.f};

    f32x4 va0, vb0, va1, vb1;
    bool okc;
    { /* tap 0: dy=-1,dx=-1 */
      okc = (i >= 1) && (j >= 1);
      const float* s = base + (okc ? (-W - 1) * 64 : 0);
      va0 = *(const f32x4*)(s);      vb0 = *(const f32x4*)(s + 4);
      va1 = *(const f32x4*)(s + 32); vb1 = *(const f32x4*)(s + 36);
    }
#pragma unroll
    for (int ks = 0; ks < 9; ks++) {
      f32x4 z = (f32x4){0.f, 0.f, 0.f, 0.f};
      f32x4 a0 = okc ? va0 : z, c0 = okc ? vb0 : z;
      f32x4 a1 = okc ? va1 : z, c1 = okc ? vb1 : z;
      union { unsigned u[4]; bf16x8 f; } f0, f1;
      f0.u[0] = pack2(a0[0], a0[1]); f0.u[1] = pack2(a0[2], a0[3]);
      f0.u[2] = pack2(c0[0], c0[1]); f0.u[3] = pack2(c0[2], c0[3]);
      f1.u[0] = pack2(a1[0], a1[1]); f1.u[1] = pack2(a1[2], a1[3]);
      f1.u[2] = pack2(c1[0], c1[1]); f1.u[3] = pack2(c1[2], c1[3]);
      if (ks < 8) { /* prefetch next tap */
        int kn = ks + 1, dy = kn / 3 - 1, dx = kn % 3 - 1;
        okc = ((unsigned)(i + dy) < (unsigned)H) && ((unsigned)(j + dx) < (unsigned)W);
        const float* s = base + (okc ? (dy * W + dx) * 64 : 0);
        va0 = *(const f32x4*)(s);      vb0 = *(const f32x4*)(s + 4);
        va1 = *(const f32x4*)(s + 32); vb1 = *(const f32x4*)(s + 36);
      }
      bf16x8 bf00 = ((const bf16x8*)wdbo)[((ks * 2 + 0) * 2 + 0) * 64 + lane];
      bf16x8 bf01 = ((const bf16x8*)wdbo)[((ks * 2 + 0) * 2 + 1) * 64 + lane];
      bf16x8 bf10 = ((const bf16x8*)wdbo)[((ks * 2 + 1) * 2 + 0) * 64 + lane];
      bf16x8 bf11 = ((const bf16x8*)wdbo)[((ks * 2 + 1) * 2 + 1) * 64 + lane];
      acc2[0] = __builtin_amdgcn_mfma_f32_16x16x32_bf16(f0.f, bf00, acc2[0], 0, 0, 0);
      acc2[1] = __builtin_amdgcn_mfma_f32_16x16x32_bf16(f0.f, bf01, acc2[1], 0, 0, 0);
      acc2[0] = __builtin_amdgcn_mfma_f32_16x16x32_bf16(f1.f, bf10, acc2[0], 0, 0, 0);
      acc2[1] = __builtin_amdgcn_mfma_f32_16x16x32_bf16(f1.f, bf11, acc2[1], 0, 0, 0);
    }
    float* sP = (float*)R2;
    float bo0 = boff[l15];
    float bo1 = (16 + l15 < 18) ? boff[16 + l15] : 0.f;
#pragma unroll
    for (int reg = 0; reg < 4; reg++) {
      int mm = qq * 16 + quad * 4 + reg;
      sP[mm * 34 + l15]      = acc2[0][reg] + bo0;
      sP[mm * 34 + 16 + l15] = acc2[1][reg] + bo1;
    }
  }
  __syncthreads();

  /* ===== phase B: tap precompute (wave qq handles k = qq, qq+4, ...) ===== */
  {
    const float* sP = (const float*)R2;
    int2 (*tiw)[4] = (int2(*)[4])R1;
    int hw = hw0 + lane;
    int i = hw / W, j = hw - i * W;
    for (int k = qq; k < 9; k += 4) {
      float dy = sP[lane * 34 + 2 * k + 0];
      float dx = sP[lane * 34 + 2 * k + 1];
      float py = (float)(i + k / 3 - 1) + dy;
      float px = (float)(j + k % 3 - 1) + dx;
      float y0f = floorf(py), x0f = floorf(px);
      int y0 = (int)y0f, x0 = (int)x0f;
      float fy = py - y0f, fx = px - x0f;
      float w00 = (1.f - fy) * (1.f - fx), w01 = (1.f - fy) * fx;
      float w10 = fy * (1.f - fx), w11 = fy * fx;
      bool vy0 = (y0 >= 0) && (y0 < H), vy1 = (y0 + 1 >= 0) && (y0 + 1 < H);
      bool vx0 = (x0 >= 0) && (x0 < W), vx1 = (x0 + 1 >= 0) && (x0 + 1 < W);
      if (!(vy0 && vx0)) w00 = 0.f;
      if (!(vy0 && vx1)) w01 = 0.f;
      if (!(vy1 && vx0)) w10 = 0.f;
      if (!(vy1 && vx1)) w11 = 0.f;
      int yi0 = min(max(y0, 0), H - 1), yi1 = min(max(y0 + 1, 0), H - 1);
      int xi0 = min(max(x0, 0), W - 1), xi1 = min(max(x0 + 1, 0), W - 1);
      int e = k * 64 + lane;
      tiw[e][0] = make_int2((yi0 * W + xi0) * 256, __float_as_int(w00));
      tiw[e][1] = make_int2((yi0 * W + xi1) * 256, __float_as_int(w01));
      tiw[e][2] = make_int2((yi1 * W + xi0) * 256, __float_as_int(w10));
      tiw[e][3] = make_int2((yi1 * W + xi1) * 256, __float_as_int(w11));
    }
  }
  __syncthreads();

  /* ===== phase C: deformable conv main loop, ring of 4 named Slot structs ===== */
  short* sAb = (short*)R2;                 /* single [64][72] bf16 A-tile */
  const int2 (*tiw)[4] = (const int2(*)[4])R1;
  const char* fb = (const char*)fcl + (size_t)b * HW * 256;
  int c2 = lane & 31;          /* channel pair: channels 2c2, 2c2+1 */
  int c28 = c2 * 8;
  int half = lane >> 5;
  int parow = qq * 16 + half;  /* pa = parow + pp*2 */

  struct Slot { float2 v0, v1, v2, v3; float w0, w1, w2, w3; };
  Slot s0, s1, s2, s3;

  auto issue = [&](Slot& s, int ks, int pp) {
    int e = ks * 64 + parow + pp * 2;
    int4 q0 = *(const int4*)&tiw[e][0];
    int4 q1 = *(const int4*)&tiw[e][2];
    s.v0 = *(const float2*)(fb + (q0.x + c28)); s.w0 = __int_as_float(q0.y);
    s.v1 = *(const float2*)(fb + (q0.z + c28)); s.w1 = __int_as_float(q0.w);
    s.v2 = *(const float2*)(fb + (q1.x + c28)); s.w2 = __int_as_float(q1.y);
    s.v3 = *(const float2*)(fb + (q1.z + c28)); s.w3 = __int_as_float(q1.w);
  };
  auto consume = [&](const Slot& s, int pp) {
    int pa = parow + pp * 2;
    float slo = s.w0 * s.v0.x + s.w1 * s.v1.x + s.w2 * s.v2.x + s.w3 * s.v3.x;
    float shi = s.w0 * s.v0.y + s.w1 * s.v1.y + s.w2 * s.v2.y + s.w3 * s.v3.y;
    ((unsigned*)sAb)[pa * 36 + c2] = pack2(slo, shi);
  };

  f32x4 acc3[4];
#pragma unroll
  for (int nt = 0; nt < 4; nt++) acc3[nt] = (f32x4){0.f, 0.f, 0.f, 0.f};

  auto mfmastep = [&](int ks) {
#pragma unroll
    for (int ch = 0; ch < 2; ch++) {
      bf16x8 af = *(const bf16x8*)&sAb[mrow * 72 + ch * 32 + quad * 8];
      int kc = ks * 2 + ch;
#pragma unroll
      for (int nt = 0; nt < 4; nt++) {
        bf16x8 bf = ((const bf16x8*)wdb3)[(kc * 4 + nt) * 64 + lane];
        acc3[nt] = __builtin_amdgcn_mfma_f32_16x16x32_bf16(af, bf, acc3[nt], 0, 0, 0);
      }
    }
  };

  issue(s0, 0, 0); issue(s1, 0, 1); issue(s2, 0, 2); issue(s3, 0, 3);
  for (int ks = 0; ks < 8; ks++) {
    consume(s0, 0); issue(s0, ks, 4);
    consume(s1, 1); issue(s1, ks, 5);
    consume(s2, 2); issue(s2, ks, 6);
    consume(s3, 3); issue(s3, ks, 7);
    consume(s0, 4); issue(s0, ks + 1, 0);
    consume(s1, 5); issue(s1, ks + 1, 1);
    consume(s2, 6); issue(s2, ks + 1, 2);
    consume(s3, 7); issue(s3, ks + 1, 3);
    mfmastep(ks);
  }
  /* drain: ks = 8 */
  consume(s0, 0); issue(s0, 8, 4);
  consume(s1, 1); issue(s1, 8, 5);
  consume(s2, 2); issue(s2, 8, 6);
  consume(s3, 3); issue(s3, 8, 7);
  consume(s0, 4); consume(s1, 5); consume(s2, 6); consume(s3, 7);
  mfmastep(8);

  /* ===== phase D: BN + bf16 into sAb rows (wave-private) ===== */
#pragma unroll
  for (int nt = 0; nt < 4; nt++) {
    int o = nt * 16 + l15;
    float sc = bns[o], sb = bnb[o], bb = bd[o];
#pragma unroll
    for (int reg = 0; reg < 4; reg++) {
      int m = qq * 16 + quad * 4 + reg;
      sAb[m * 72 + o] = f2bf((acc3[nt][reg] + bb) * sc + sb);
    }
  }
  /* no barrier: phase-E A-frag reads are wave-private rows */

  /* ===== phase E+F: pwconv2 chunked (4 x 64 out-ch) + gate epilogue ===== */
  bf16x8 af0 = *(const bf16x8*)&sAb[mrow * 72 + quad * 8];
  bf16x8 af1 = *(const bf16x8*)&sAb[mrow * 72 + 32 + quad * 8];
  float* sA = (float*)R1;   /* [64 o][68 p]; tiw dead; barrier below protects */
  for (int nc = 0; nc < 4; nc++) {
    f32x4 acc4[4];
#pragma unroll
    for (int nt2 = 0; nt2 < 4; nt2++) acc4[nt2] = (f32x4){0.f, 0.f, 0.f, 0.f};
#pragma unroll
    for (int nt2 = 0; nt2 < 4; nt2++) {
      int nt = nc * 4 + nt2;
      bf16x8 bf0 = ((const bf16x8*)wdb2)[nt * 64 + lane];
      bf16x8 bf1 = ((const bf16x8*)wdb2)[(16 + nt) * 64 + lane];
      acc4[nt2] = __builtin_amdgcn_mfma_f32_16x16x32_bf16(af0, bf0, acc4[nt2], 0, 0, 0);
      acc4[nt2] = __builtin_amdgcn_mfma_f32_16x16x32_bf16(af1, bf1, acc4[nt2], 0, 0, 0);
    }
    __syncthreads();
#pragma unroll
    for (int nt2 = 0; nt2 < 4; nt2++) {
      int o1 = nt2 * 16 + l15;
      float bias = b2[nc * 64 + o1];
#pragma unroll
      for (int reg = 0; reg < 4; reg++) {
        int m = qq * 16 + quad * 4 + reg;
        sA[o1 * 68 + m] = acc4[nt2][reg] + bias;   /* transposed stage */
      }
    }
    __syncthreads();
#pragma unroll
    for (int it = 0; it < 4; it++) {
      int rr = it * 256 + t;
      int o1 = rr >> 4, pg = (rr & 15) * 4;
      f32x4 v = *(const f32x4*)&sA[o1 * 68 + pg];
      int o = nc * 64 + o1;
      size_t gi = ((size_t)b * CIN + o) * HW + hw0 + pg;
      f32x4 xv = *(const f32x4*)&x[gi];
      f32x4 r;
#pragma unroll
      for (int u = 0; u < 4; u++) {
        float sg = 1.f / (1.f + __expf(-v[u]));
        r[u] = xv[u] * sg;
      }
      *(f32x4*)&out[gi] = r;
    }
  }
}

extern "C" void kernel_launch(void* const* d_in, const int* in_sizes, int n_in,
                              void* d_out, int out_size, void* d_ws, size_t ws_size,
                              hipStream_t stream) {
  const float* x     = (const float*)d_in[0];
  const float* w1    = (const float*)d_in[1];
  const float* b1    = (const float*)d_in[2];
  const float* woff  = (const float*)d_in[3];
  const float* boff  = (const float*)d_in[4];
  const float* wd    = (const float*)d_in[5];
  const float* bd    = (const float*)d_in[6];
  const float* gamma = (const float*)d_in[7];
  const float* beta  = (const float*)d_in[8];
  const float* rmean = (const float*)d_in[9];
  const float* rvar  = (const float*)d_in[10];
  const float* w2    = (const float*)d_in[11];
  const float* b2    = (const float*)d_in[12];
  float* out = (float*)d_out;
  float* ws  = (float*)d_ws;

  dim3 blk(256);
  k0_prep<<<dim3(345), blk, 0, stream>>>(w1, woff, wd, w2, gamma, beta, rmean, rvar, ws);
  k1_pw1<<<dim3(NBLK), blk, 0, stream>>>(x, (const short*)(ws + OFF_WDB1), b1, ws + OFF_FCL);
  k234<<<dim3(NBLK), blk, 0, stream>>>(ws + OFF_FCL, (const short*)(ws + OFF_WDBO), boff,
                                       (const short*)(ws + OFF_WDB3), bd,
                                       ws + OFF_BNS, ws + OFF_BNB,
                                       (const short*)(ws + OFF_WDB2), b2, x, out);
}